// Round 7
// baseline (105.393 us; speedup 1.0000x reference)
//
#include <hip/hip_runtime.h>
#include <hip/hip_bf16.h>

// ContrastiveLoss (NT-Xent): B=2048, D=256, T=0.5
// loss = mean_i [ -2*dot(zh_i, zh_pos(i)) + log( sum_j exp(2*dot(zh_i, zh_j)) - e^2 ) ]
// v5: TWO ordinary launches (cooperative grid.sync failed in-harness: out never
// written -> absmax == full loss value).
//   K1 (512 blocks): row-pair L2-normalize -> zb (bf16), zb2 (bf16*2log2e),
//       pos-dots pd; zero S, cnt.
//   K2 (528 blocks): 2 consecutive upper-tri 128x64 exp2-tiles per block
//       (1056 tiles exactly; tiles-per-panel is even so both tiles share one
//       128-row panel -> A-fragments loaded once). B strip async-staged via
//       global_load_lds w=16, XOR-swizzled source + swizzled ds_read. Row sums
//       always; col sums (LDS cs[64]) for strictly-upper tiles; atomics into S.
//       TAIL: release fence + atomicAdd(cnt); LAST block acquire-fences and
//       computes loss = mean log(S[i]-e^2) - 2*pd over all 4096 rows -> out.
//       (fence-counter pattern: no spin, no co-residency assumption)
// A-side bf16 pre-scaled by 2*log2(e) so exp(2*sim) = exp2(dot) -> bare v_exp_f32.

typedef __attribute__((ext_vector_type(8))) short short8;
typedef __attribute__((ext_vector_type(4))) float float4v;

#define NROWS 4096
#define DIM 256
#define NB 2048
#define TEMP_INV 2.0f
#define SCALE 2.8853900817779268f  // 2*log2(e)
#define NBLOCKS 528               // 2 tiles each; 1056 = sum_{ib<32}(64-2*ib)

static __device__ __forceinline__ unsigned short f2bf_rne(float f) {
    unsigned int x = __float_as_uint(f);
    unsigned int r = x + 0x7FFFu + ((x >> 16) & 1u);
    return (unsigned short)(r >> 16);
}

static __device__ __forceinline__ void decode_tile(int tidx, int& ib, int& jc) {
    int rem = tidx; ib = 0;
    while (rem >= 64 - 2 * ib) { rem -= 64 - 2 * ib; ib++; }
    jc = 2 * ib + rem;
}

// K1: normalize pair (p, p+NB); zero S and cnt. grid 512 x 256.
__global__ __launch_bounds__(256) void k_norm(const float* __restrict__ zi,
                                              const float* __restrict__ zj,
                                              unsigned short* __restrict__ zb,
                                              unsigned short* __restrict__ zb2,
                                              float* __restrict__ pd,
                                              float* __restrict__ S,
                                              unsigned int* __restrict__ cnt) {
    if (blockIdx.x == 0 && threadIdx.x == 0) *cnt = 0u;
    if (threadIdx.x < 8) S[blockIdx.x * 8 + threadIdx.x] = 0.0f;
    int wave = threadIdx.x >> 6, lane = threadIdx.x & 63;
    int p = blockIdx.x * 4 + wave;  // pair index: rows p and p+NB
    float4 vi = *(const float4*)(zi + (size_t)p * DIM + lane * 4);
    float4 vj = *(const float4*)(zj + (size_t)p * DIM + lane * 4);
    float ssi = vi.x * vi.x + vi.y * vi.y + vi.z * vi.z + vi.w * vi.w;
    float ssj = vj.x * vj.x + vj.y * vj.y + vj.z * vj.z + vj.w * vj.w;
    float dij = vi.x * vj.x + vi.y * vj.y + vi.z * vj.z + vi.w * vj.w;
    #pragma unroll
    for (int off = 32; off > 0; off >>= 1) {
        ssi += __shfl_xor(ssi, off);
        ssj += __shfl_xor(ssj, off);
        dij += __shfl_xor(dij, off);
    }
    float si = 1.0f / fmaxf(sqrtf(ssi), 1e-12f);
    float sj = 1.0f / fmaxf(sqrtf(ssj), 1e-12f);
    ushort4 a, b;
    a.x = f2bf_rne(vi.x * si); a.y = f2bf_rne(vi.y * si);
    a.z = f2bf_rne(vi.z * si); a.w = f2bf_rne(vi.w * si);
    b.x = f2bf_rne(vj.x * sj); b.y = f2bf_rne(vj.y * sj);
    b.z = f2bf_rne(vj.z * sj); b.w = f2bf_rne(vj.w * sj);
    *(ushort4*)(zb + (size_t)p * DIM + lane * 4) = a;
    *(ushort4*)(zb + (size_t)(p + NB) * DIM + lane * 4) = b;
    float ki = si * SCALE, kj = sj * SCALE;
    ushort4 a2, b2;
    a2.x = f2bf_rne(vi.x * ki); a2.y = f2bf_rne(vi.y * ki);
    a2.z = f2bf_rne(vi.z * ki); a2.w = f2bf_rne(vi.w * ki);
    b2.x = f2bf_rne(vj.x * kj); b2.y = f2bf_rne(vj.y * kj);
    b2.z = f2bf_rne(vj.z * kj); b2.w = f2bf_rne(vj.w * kj);
    *(ushort4*)(zb2 + (size_t)p * DIM + lane * 4) = a2;
    *(ushort4*)(zb2 + (size_t)(p + NB) * DIM + lane * 4) = b2;
    if (lane == 0) pd[p] = dij * si * sj;
}

// K2: two 128x64 exp2-tiles per block + fence-counter loss tail.
__global__ __launch_bounds__(256, 3) void k_sim(const unsigned short* __restrict__ zb,
                                                const unsigned short* __restrict__ zb2,
                                                const float* __restrict__ pd,
                                                float* __restrict__ S,
                                                unsigned int* __restrict__ cnt,
                                                float* __restrict__ out) {
    __shared__ __attribute__((aligned(1024))) short Bs[64 * 256];  // 32 KB linear rows
    __shared__ float cs[64];
    __shared__ float red[4];
    __shared__ int lastflag;

    int tid = threadIdx.x, wave = tid >> 6, lane = tid & 63;
    int m = lane & 15, q = lane >> 4;
    const short* zsB = (const short*)zb;
    const short* zsA = (const short*)zb2;

    int ib0, jc0, ib1, jc1;
    decode_tile(blockIdx.x * 2, ib0, jc0);
    decode_tile(blockIdx.x * 2 + 1, ib1, jc1);

    short8 A[2][8];
    int a_ib = -1;  // which row-panel A currently holds
    int swz = m & 7;

    #pragma unroll
    for (int t = 0; t < 2; t++) {
        int ib = t ? ib1 : ib0;
        int jc = t ? jc1 : jc0;
        bool do_col = (jc >= 2 * ib + 2);
        int ibase = ib * 128 + wave * 32;
        int jbase = jc * 64;

        __syncthreads();  // protect Bs/cs reuse across the two tiles
        if (tid < 64) cs[tid] = 0.0f;

        // Async-stage 64 B-rows (512B each) into LDS. Each global_load_lds
        // writes 1024B = 2 rows linearly (lane -> base + lane*16). Source slot
        // pre-swizzled (slot ^ (row&7)); read side applies the same XOR.
        {
            int s = lane & 31;      // 16B slot within row
            int rhalf = lane >> 5;  // 0 or 1
            #pragma unroll
            for (int c = 0; c < 8; c++) {
                int r = wave * 16 + c * 2 + rhalf;  // local row 0..63
                const short* gsrc = zsB + (size_t)(jbase + r) * DIM + ((s ^ (r & 7)) * 8);
                short* ldst = &Bs[(wave * 16 + c * 2) * 256];  // wave-uniform base
                __builtin_amdgcn_global_load_lds(
                    (const __attribute__((address_space(1))) unsigned int*)gsrc,
                    (__attribute__((address_space(3))) unsigned int*)ldst,
                    16, 0, 0);
            }
        }

        // A fragments: A[m][k], m = lane&15, k = q*8 + tt (verified layout);
        // both tiles share the row panel (tiles-per-panel even) -> load once.
        if (ib != a_ib) {
            #pragma unroll
            for (int tt = 0; tt < 2; tt++) {
                const short* arow = zsA + (size_t)(ibase + tt * 16 + m) * DIM + q * 8;
                #pragma unroll
                for (int kk = 0; kk < 8; kk++) A[tt][kk] = *(const short8*)(arow + kk * 32);
            }
            a_ib = ib;
        }

        asm volatile("s_waitcnt vmcnt(0)" ::: "memory");
        __syncthreads();

        float rowacc[2][4] = {{0.f, 0.f, 0.f, 0.f}, {0.f, 0.f, 0.f, 0.f}};

        #pragma unroll
        for (int jt = 0; jt < 4; jt++) {
            const short* brow = &Bs[(jt * 16 + m) * 256];
            float4v c0 = {0.f, 0.f, 0.f, 0.f};
            float4v c1 = {0.f, 0.f, 0.f, 0.f};
            #pragma unroll
            for (int kk = 0; kk < 8; kk++) {
                short8 b = *(const short8*)(brow + (((q + 4 * kk) ^ swz) * 8));
                c0 = __builtin_amdgcn_mfma_f32_16x16x32_bf16(A[0][kk], b, c0, 0, 0, 0);
                c1 = __builtin_amdgcn_mfma_f32_16x16x32_bf16(A[1][kk], b, c1, 0, 0, 0);
            }
            float csum = 0.0f;
            #pragma unroll
            for (int r = 0; r < 4; r++) {
                float e0 = __builtin_exp2f(c0[r]);
                float e1 = __builtin_exp2f(c1[r]);
                rowacc[0][r] += e0; rowacc[1][r] += e1;
                csum += e0 + e1;
            }
            if (do_col) {
                // column jt*16 + m: sum over this wave's 32 rows
                csum += __shfl_xor(csum, 16);
                csum += __shfl_xor(csum, 32);
                if (lane < 16) atomicAdd(&cs[jt * 16 + m], csum);
            }
        }

        // row sums: reduce over 16 column-lanes, atomic into S
        #pragma unroll
        for (int tt = 0; tt < 2; tt++) {
            #pragma unroll
            for (int r = 0; r < 4; r++) {
                float s = rowacc[tt][r];
                s += __shfl_xor(s, 1);
                s += __shfl_xor(s, 2);
                s += __shfl_xor(s, 4);
                s += __shfl_xor(s, 8);
                if (m == 0) atomicAdd(&S[ibase + tt * 16 + q * 4 + r], s);
            }
        }
        if (do_col) {
            __syncthreads();
            if (tid < 64) atomicAdd(&S[jbase + tid], cs[tid]);
        }
    }

    // ---- fence-counter tail: last finished block computes the loss ----
    __threadfence();  // release: make this block's S atomics visible
    if (tid == 0) {
        unsigned int r = atomicAdd(cnt, 1u);
        lastflag = (r == NBLOCKS - 1) ? 1 : 0;
    }
    __syncthreads();
    if (lastflag) {
        __threadfence();  // acquire: observe all other blocks' S atomics
        const float E2 = 7.38905609893065f;  // exp(sim_ii) = e^2
        float acc = 0.0f;
        #pragma unroll
        for (int c = 0; c < NROWS / 256; c++) {
            int i = c * 256 + tid;
            acc += logf(S[i] - E2) - TEMP_INV * pd[i & (NB - 1)];
        }
        #pragma unroll
        for (int off = 32; off > 0; off >>= 1) acc += __shfl_xor(acc, off);
        if (lane == 0) red[wave] = acc;
        __syncthreads();
        if (tid == 0)
            *out = (red[0] + red[1] + red[2] + red[3]) * (1.0f / NROWS);
    }
}

extern "C" void kernel_launch(void* const* d_in, const int* in_sizes, int n_in,
                              void* d_out, int out_size, void* d_ws, size_t ws_size,
                              hipStream_t stream) {
    const float* zi = (const float*)d_in[0];
    const float* zj = (const float*)d_in[1];
    float* out = (float*)d_out;
    char* ws = (char*)d_ws;
    unsigned short* zb  = (unsigned short*)ws;                        // 2 MB bf16 normalized
    unsigned short* zb2 = (unsigned short*)(ws + 2 * 1024 * 1024);    // 2 MB bf16 * 2log2e
    float* S  = (float*)(ws + 4 * 1024 * 1024);                       // 16 KB row exp sums
    float* pd = (float*)(ws + 4 * 1024 * 1024 + 16 * 1024);           // 8 KB pos dots
    unsigned int* cnt = (unsigned int*)(ws + 4 * 1024 * 1024 + 24 * 1024);  // 4 B

    hipLaunchKernelGGL(k_norm, dim3(512), dim3(256), 0, stream, zi, zj, zb, zb2, pd, S, cnt);
    hipLaunchKernelGGL(k_sim, dim3(NBLOCKS), dim3(256), 0, stream, zb, zb2, pd, S, cnt, out);
}

// Round 8
// 80.935 us; speedup vs baseline: 1.3022x; 1.3022x over previous
//
#include <hip/hip_runtime.h>
#include <hip/hip_bf16.h>

// ContrastiveLoss (NT-Xent): B=2048, D=256, T=0.5
// loss = mean_i [ -2*dot(zh_i, zh_pos(i)) + log( sum_j exp(2*dot(zh_i, zh_j)) - e^2 ) ]
// v6: ZERO global atomics in k_sim. Round-7 counters showed k_sim = 48us with
// MfmaUtil 3% / VALUBusy 7% / HBM 4.5% -- ~90% stall, attributed to ~203K
// device-scope atomicAdds into the 16KB S array (128 cache lines, ~1600
// serialized RMWs each). Every prior version had this bottleneck.
// Fix: collision-free partial-sum stores.
//   K1 (512 blocks): row-pair L2-normalize -> zb (bf16), zb2 (bf16*2log2e),
//       pos-dots pd; zero Prow/Pcol (1.5 MB) and out.
//   K2 (1056 blocks, one 128x64 upper-tri tile each -- verified v3 body):
//       tile (ib,jc) plain-stores 128 row sums -> Prow[jc][ib*128+r] and (when
//       strictly upper) 64 col sums -> Pcol[ib][jc*64+c]. No tile pair shares a
//       slot -> no atomics, no fences. B strip async-staged via global_load_lds
//       w=16, XOR-swizzled source + swizzled ds_read.
//   K3 (16 blocks): S_i = sum_jc Prow[jc][i] + sum_ib Pcol[ib][i] (96 coalesced
//       plane reads), loss = mean log(S_i - e^2) - 2*pd[i%NB] -> out (16 atomics).
// A-side bf16 pre-scaled by 2*log2(e) so exp(2*sim) = exp2(dot) -> bare v_exp_f32.

typedef __attribute__((ext_vector_type(8))) short short8;
typedef __attribute__((ext_vector_type(4))) float float4v;

#define NROWS 4096
#define DIM 256
#define NB 2048
#define TEMP_INV 2.0f
#define SCALE 2.8853900817779268f  // 2*log2(e)
#define NTILES 1056  // sum_{ib=0}^{31} (64 - 2*ib) upper-triangular 128x64 tiles

static __device__ __forceinline__ unsigned short f2bf_rne(float f) {
    unsigned int x = __float_as_uint(f);
    unsigned int r = x + 0x7FFFu + ((x >> 16) & 1u);
    return (unsigned short)(r >> 16);
}

// K1: normalize pair (p, p+NB); zero Prow/Pcol and out. grid 512 x 256.
__global__ __launch_bounds__(256) void k_norm(const float* __restrict__ zi,
                                              const float* __restrict__ zj,
                                              unsigned short* __restrict__ zb,
                                              unsigned short* __restrict__ zb2,
                                              float* __restrict__ pd,
                                              float4* __restrict__ pzero,
                                              float* __restrict__ out) {
    if (blockIdx.x == 0 && threadIdx.x == 0) *out = 0.0f;
    // zero Prow (1 MB) + Pcol (512 KB) = 98304 float4s across 131072 threads
    {
        int g = blockIdx.x * 256 + threadIdx.x;
        if (g < 98304) {
            float4 z; z.x = 0.f; z.y = 0.f; z.z = 0.f; z.w = 0.f;
            pzero[g] = z;
        }
    }
    int wave = threadIdx.x >> 6, lane = threadIdx.x & 63;
    int p = blockIdx.x * 4 + wave;  // pair index: rows p and p+NB
    float4 vi = *(const float4*)(zi + (size_t)p * DIM + lane * 4);
    float4 vj = *(const float4*)(zj + (size_t)p * DIM + lane * 4);
    float ssi = vi.x * vi.x + vi.y * vi.y + vi.z * vi.z + vi.w * vi.w;
    float ssj = vj.x * vj.x + vj.y * vj.y + vj.z * vj.z + vj.w * vj.w;
    float dij = vi.x * vj.x + vi.y * vj.y + vi.z * vj.z + vi.w * vj.w;
    #pragma unroll
    for (int off = 32; off > 0; off >>= 1) {
        ssi += __shfl_xor(ssi, off);
        ssj += __shfl_xor(ssj, off);
        dij += __shfl_xor(dij, off);
    }
    float si = 1.0f / fmaxf(sqrtf(ssi), 1e-12f);
    float sj = 1.0f / fmaxf(sqrtf(ssj), 1e-12f);
    ushort4 a, b;
    a.x = f2bf_rne(vi.x * si); a.y = f2bf_rne(vi.y * si);
    a.z = f2bf_rne(vi.z * si); a.w = f2bf_rne(vi.w * si);
    b.x = f2bf_rne(vj.x * sj); b.y = f2bf_rne(vj.y * sj);
    b.z = f2bf_rne(vj.z * sj); b.w = f2bf_rne(vj.w * sj);
    *(ushort4*)(zb + (size_t)p * DIM + lane * 4) = a;
    *(ushort4*)(zb + (size_t)(p + NB) * DIM + lane * 4) = b;
    float ki = si * SCALE, kj = sj * SCALE;
    ushort4 a2, b2;
    a2.x = f2bf_rne(vi.x * ki); a2.y = f2bf_rne(vi.y * ki);
    a2.z = f2bf_rne(vi.z * ki); a2.w = f2bf_rne(vi.w * ki);
    b2.x = f2bf_rne(vj.x * kj); b2.y = f2bf_rne(vj.y * kj);
    b2.z = f2bf_rne(vj.z * kj); b2.w = f2bf_rne(vj.w * kj);
    *(ushort4*)(zb2 + (size_t)p * DIM + lane * 4) = a2;
    *(ushort4*)(zb2 + (size_t)(p + NB) * DIM + lane * 4) = b2;
    if (lane == 0) pd[p] = dij * si * sj;
}

// K2: one upper-triangular 128x64 exp2-tile per block (v3 body); partial-sum
// stores instead of atomics. Tile decode: ib in [0,32), jc in [2*ib, 64).
__global__ __launch_bounds__(256, 3) void k_sim(const unsigned short* __restrict__ zb,
                                                const unsigned short* __restrict__ zb2,
                                                float* __restrict__ Prow,
                                                float* __restrict__ Pcol) {
    __shared__ __attribute__((aligned(1024))) short Bs[64 * 256];  // 32 KB linear rows
    __shared__ float cs[64];
    int rem = blockIdx.x, ib = 0;
    while (rem >= 64 - 2 * ib) { rem -= 64 - 2 * ib; ib++; }
    int jc = 2 * ib + rem;
    bool do_col = (jc >= 2 * ib + 2);

    int tid = threadIdx.x, wave = tid >> 6, lane = tid & 63;
    int m = lane & 15, q = lane >> 4;
    const short* zsB = (const short*)zb;
    const short* zsA = (const short*)zb2;
    int ibase = ib * 128 + wave * 32;
    int jbase = jc * 64;

    if (tid < 64) cs[tid] = 0.0f;

    // Async-stage 64 B-rows (512B each) into LDS. Each global_load_lds writes
    // 1024B = 2 rows linearly (lane -> base + lane*16). Source slot pre-swizzled
    // (slot ^ (row&7)); read side applies the same XOR.
    {
        int s = lane & 31;      // 16B slot within row
        int rhalf = lane >> 5;  // 0 or 1
        #pragma unroll
        for (int c = 0; c < 8; c++) {
            int r = wave * 16 + c * 2 + rhalf;  // local row 0..63
            const short* gsrc = zsB + (size_t)(jbase + r) * DIM + ((s ^ (r & 7)) * 8);
            short* ldst = &Bs[(wave * 16 + c * 2) * 256];  // wave-uniform base
            __builtin_amdgcn_global_load_lds(
                (const __attribute__((address_space(1))) unsigned int*)gsrc,
                (__attribute__((address_space(3))) unsigned int*)ldst,
                16, 0, 0);
        }
    }

    // A fragments: A[m][k], m = lane&15, k = q*8 + t  (verified 16x16x32 layout)
    short8 A[2][8];
    #pragma unroll
    for (int t = 0; t < 2; t++) {
        const short* arow = zsA + (size_t)(ibase + t * 16 + m) * DIM + q * 8;
        #pragma unroll
        for (int kk = 0; kk < 8; kk++) A[t][kk] = *(const short8*)(arow + kk * 32);
    }

    asm volatile("s_waitcnt vmcnt(0)" ::: "memory");
    __syncthreads();

    float rowacc[2][4] = {{0.f, 0.f, 0.f, 0.f}, {0.f, 0.f, 0.f, 0.f}};
    int swz = m & 7;

    #pragma unroll
    for (int jt = 0; jt < 4; jt++) {
        const short* brow = &Bs[(jt * 16 + m) * 256];
        float4v c0 = {0.f, 0.f, 0.f, 0.f};
        float4v c1 = {0.f, 0.f, 0.f, 0.f};
        #pragma unroll
        for (int kk = 0; kk < 8; kk++) {
            short8 b = *(const short8*)(brow + (((q + 4 * kk) ^ swz) * 8));
            c0 = __builtin_amdgcn_mfma_f32_16x16x32_bf16(A[0][kk], b, c0, 0, 0, 0);
            c1 = __builtin_amdgcn_mfma_f32_16x16x32_bf16(A[1][kk], b, c1, 0, 0, 0);
        }
        float csum = 0.0f;
        #pragma unroll
        for (int r = 0; r < 4; r++) {
            float e0 = __builtin_exp2f(c0[r]);
            float e1 = __builtin_exp2f(c1[r]);
            rowacc[0][r] += e0; rowacc[1][r] += e1;
            csum += e0 + e1;
        }
        if (do_col) {
            // column jt*16 + m: sum over this wave's 32 rows (LDS combine only)
            csum += __shfl_xor(csum, 16);
            csum += __shfl_xor(csum, 32);
            if (lane < 16) atomicAdd(&cs[jt * 16 + m], csum);
        }
    }

    // row sums: reduce over 16 column-lanes, plain store into Prow[jc][row]
    #pragma unroll
    for (int t = 0; t < 2; t++) {
        #pragma unroll
        for (int r = 0; r < 4; r++) {
            float s = rowacc[t][r];
            s += __shfl_xor(s, 1);
            s += __shfl_xor(s, 2);
            s += __shfl_xor(s, 4);
            s += __shfl_xor(s, 8);
            if (m == 0) Prow[jc * NROWS + ibase + t * 16 + q * 4 + r] = s;
        }
    }
    if (do_col) {
        __syncthreads();
        if (tid < 64) Pcol[ib * NROWS + jbase + tid] = cs[tid];
    }
}

// K3: S_i = sum of 96 partial planes; loss = mean log(S_i - e^2) - 2*pd[i%NB].
// grid 16 x 256.
__global__ __launch_bounds__(256) void k_loss(const float* __restrict__ Prow,
                                              const float* __restrict__ Pcol,
                                              const float* __restrict__ pd,
                                              float* __restrict__ out) {
    __shared__ float red[4];
    int wave = threadIdx.x >> 6, lane = threadIdx.x & 63;
    int i = blockIdx.x * 256 + threadIdx.x;
    float s = 0.0f;
    #pragma unroll
    for (int jc = 0; jc < 64; jc++) s += Prow[jc * NROWS + i];
    #pragma unroll
    for (int ib = 0; ib < 32; ib++) s += Pcol[ib * NROWS + i];
    const float E2 = 7.38905609893065f;  // exp(sim_ii) = e^2
    float term = logf(s - E2) - TEMP_INV * pd[i & (NB - 1)];
    #pragma unroll
    for (int off = 32; off > 0; off >>= 1) term += __shfl_xor(term, off);
    if (lane == 0) red[wave] = term;
    __syncthreads();
    if (threadIdx.x == 0) {
        float t = (red[0] + red[1] + red[2] + red[3]) * (1.0f / NROWS);
        atomicAdd(out, t);
    }
}

extern "C" void kernel_launch(void* const* d_in, const int* in_sizes, int n_in,
                              void* d_out, int out_size, void* d_ws, size_t ws_size,
                              hipStream_t stream) {
    const float* zi = (const float*)d_in[0];
    const float* zj = (const float*)d_in[1];
    float* out = (float*)d_out;
    char* ws = (char*)d_ws;
    unsigned short* zb  = (unsigned short*)ws;                          // 2 MB bf16 normalized
    unsigned short* zb2 = (unsigned short*)(ws + 2 * 1024 * 1024);      // 2 MB bf16 * 2log2e
    float* Prow = (float*)(ws + 4 * 1024 * 1024);                       // [64][4096] = 1 MB
    float* Pcol = (float*)(ws + 5 * 1024 * 1024);                       // [32][4096] = 512 KB
    float* pd   = (float*)(ws + 5 * 1024 * 1024 + 512 * 1024);          // 8 KB pos dots

    hipLaunchKernelGGL(k_norm, dim3(512), dim3(256), 0, stream,
                       zi, zj, zb, zb2, pd, (float4*)Prow, out);
    hipLaunchKernelGGL(k_sim, dim3(NTILES), dim3(256), 0, stream, zb, zb2, Prow, Pcol);
    hipLaunchKernelGGL(k_loss, dim3(16), dim3(256), 0, stream, Prow, Pcol, pd, out);
}

// Round 10
// 78.241 us; speedup vs baseline: 1.3470x; 1.0344x over previous
//
#include <hip/hip_runtime.h>
#include <hip/hip_bf16.h>

// ContrastiveLoss (NT-Xent): B=2048, D=256, T=0.5
// loss = mean_i [ -2*dot(zh_i, zh_pos(i)) + log( sum_j exp(2*dot(zh_i, zh_j)) - e^2 ) ]
// v7: v6 minus latency stalls. v6 counters-arithmetic: k_sim ~24us vs ~3us compute
// floor; v5's direct profile showed latency-bound at 16% occupancy, FETCH 3.7x
// working set (cross-XCD misses -> HBM ~900cyc). Fixes:
//  (1) k_sim __launch_bounds__(256,4): 4 blocks/CU (VGPR 80<=128, LDS 130<=160KB);
//      1056 blocks = one ~full residency round, 16 waves/CU latency hiding.
//  (2) XCD-chunked block swizzle (1056%8==0): consecutive tiles share the A
//      row-panel -> panel stays in that XCD's L2 (cuts HBM re-fetch).
//  (3) k_loss 16->64 blocks (4 plane-quarters/row, LDS combine).
// Structure otherwise identical to v6 (verified): collision-free partial sums,
// no global atomics in k_sim; B strip via global_load_lds w=16 with XOR-swizzled
// source + swizzled ds_read; A-side bf16 pre-scaled by 2*log2(e) -> exp2 = v_exp_f32.

typedef __attribute__((ext_vector_type(8))) short short8;
typedef __attribute__((ext_vector_type(4))) float float4v;

#define NROWS 4096
#define DIM 256
#define NB 2048
#define TEMP_INV 2.0f
#define SCALE 2.8853900817779268f  // 2*log2(e)
#define NTILES 1056  // sum_{ib=0}^{31} (64 - 2*ib) upper-triangular 128x64 tiles

static __device__ __forceinline__ unsigned short f2bf_rne(float f) {
    unsigned int x = __float_as_uint(f);
    unsigned int r = x + 0x7FFFu + ((x >> 16) & 1u);
    return (unsigned short)(r >> 16);
}

// K1: normalize pair (p, p+NB); zero Pall (1.5 MB) and out. grid 512 x 256.
__global__ __launch_bounds__(256) void k_norm(const float* __restrict__ zi,
                                              const float* __restrict__ zj,
                                              unsigned short* __restrict__ zb,
                                              unsigned short* __restrict__ zb2,
                                              float* __restrict__ pd,
                                              float4* __restrict__ pzero,
                                              float* __restrict__ out) {
    if (blockIdx.x == 0 && threadIdx.x == 0) *out = 0.0f;
    // zero Pall = 96 planes x 4096 floats = 98304 float4s across 131072 threads
    {
        int g = blockIdx.x * 256 + threadIdx.x;
        if (g < 98304) {
            float4 z; z.x = 0.f; z.y = 0.f; z.z = 0.f; z.w = 0.f;
            pzero[g] = z;
        }
    }
    int wave = threadIdx.x >> 6, lane = threadIdx.x & 63;
    int p = blockIdx.x * 4 + wave;  // pair index: rows p and p+NB
    float4 vi = *(const float4*)(zi + (size_t)p * DIM + lane * 4);
    float4 vj = *(const float4*)(zj + (size_t)p * DIM + lane * 4);
    float ssi = vi.x * vi.x + vi.y * vi.y + vi.z * vi.z + vi.w * vi.w;
    float ssj = vj.x * vj.x + vj.y * vj.y + vj.z * vj.z + vj.w * vj.w;
    float dij = vi.x * vj.x + vi.y * vj.y + vi.z * vj.z + vi.w * vj.w;
    #pragma unroll
    for (int off = 32; off > 0; off >>= 1) {
        ssi += __shfl_xor(ssi, off);
        ssj += __shfl_xor(ssj, off);
        dij += __shfl_xor(dij, off);
    }
    float si = 1.0f / fmaxf(sqrtf(ssi), 1e-12f);
    float sj = 1.0f / fmaxf(sqrtf(ssj), 1e-12f);
    ushort4 a, b;
    a.x = f2bf_rne(vi.x * si); a.y = f2bf_rne(vi.y * si);
    a.z = f2bf_rne(vi.z * si); a.w = f2bf_rne(vi.w * si);
    b.x = f2bf_rne(vj.x * sj); b.y = f2bf_rne(vj.y * sj);
    b.z = f2bf_rne(vj.z * sj); b.w = f2bf_rne(vj.w * sj);
    *(ushort4*)(zb + (size_t)p * DIM + lane * 4) = a;
    *(ushort4*)(zb + (size_t)(p + NB) * DIM + lane * 4) = b;
    float ki = si * SCALE, kj = sj * SCALE;
    ushort4 a2, b2;
    a2.x = f2bf_rne(vi.x * ki); a2.y = f2bf_rne(vi.y * ki);
    a2.z = f2bf_rne(vi.z * ki); a2.w = f2bf_rne(vi.w * ki);
    b2.x = f2bf_rne(vj.x * kj); b2.y = f2bf_rne(vj.y * kj);
    b2.z = f2bf_rne(vj.z * kj); b2.w = f2bf_rne(vj.w * kj);
    *(ushort4*)(zb2 + (size_t)p * DIM + lane * 4) = a2;
    *(ushort4*)(zb2 + (size_t)(p + NB) * DIM + lane * 4) = b2;
    if (lane == 0) pd[p] = dij * si * sj;
}

// K2: one upper-triangular 128x64 exp2-tile per block; partial-sum stores.
// Tile decode: ib in [0,32), jc in [2*ib, 64).
__global__ __launch_bounds__(256, 4) void k_sim(const unsigned short* __restrict__ zb,
                                                const unsigned short* __restrict__ zb2,
                                                float* __restrict__ Prow,
                                                float* __restrict__ Pcol) {
    __shared__ __attribute__((aligned(1024))) short Bs[64 * 256];  // 32 KB linear rows
    __shared__ float cs[64];
    // XCD-chunked swizzle (bijective: 1056 % 8 == 0, chunk = 132): consecutive
    // tiles (sharing an A row-panel) land on the same XCD's L2.
    int bid = blockIdx.x;
    int swb = (bid & 7) * 132 + (bid >> 3);
    int rem = swb, ib = 0;
    while (rem >= 64 - 2 * ib) { rem -= 64 - 2 * ib; ib++; }
    int jc = 2 * ib + rem;
    bool do_col = (jc >= 2 * ib + 2);

    int tid = threadIdx.x, wave = tid >> 6, lane = tid & 63;
    int m = lane & 15, q = lane >> 4;
    const short* zsB = (const short*)zb;
    const short* zsA = (const short*)zb2;
    int ibase = ib * 128 + wave * 32;
    int jbase = jc * 64;

    if (tid < 64) cs[tid] = 0.0f;

    // Async-stage 64 B-rows (512B each) into LDS. Each global_load_lds writes
    // 1024B = 2 rows linearly (lane -> base + lane*16). Source slot pre-swizzled
    // (slot ^ (row&7)); read side applies the same XOR.
    {
        int s = lane & 31;      // 16B slot within row
        int rhalf = lane >> 5;  // 0 or 1
        #pragma unroll
        for (int c = 0; c < 8; c++) {
            int r = wave * 16 + c * 2 + rhalf;  // local row 0..63
            const short* gsrc = zsB + (size_t)(jbase + r) * DIM + ((s ^ (r & 7)) * 8);
            short* ldst = &Bs[(wave * 16 + c * 2) * 256];  // wave-uniform base
            __builtin_amdgcn_global_load_lds(
                (const __attribute__((address_space(1))) unsigned int*)gsrc,
                (__attribute__((address_space(3))) unsigned int*)ldst,
                16, 0, 0);
        }
    }

    // A fragments: A[m][k], m = lane&15, k = q*8 + t  (verified 16x16x32 layout)
    short8 A[2][8];
    #pragma unroll
    for (int t = 0; t < 2; t++) {
        const short* arow = zsA + (size_t)(ibase + t * 16 + m) * DIM + q * 8;
        #pragma unroll
        for (int kk = 0; kk < 8; kk++) A[t][kk] = *(const short8*)(arow + kk * 32);
    }

    asm volatile("s_waitcnt vmcnt(0)" ::: "memory");
    __syncthreads();

    float rowacc[2][4] = {{0.f, 0.f, 0.f, 0.f}, {0.f, 0.f, 0.f, 0.f}};
    int swz = m & 7;

    #pragma unroll
    for (int jt = 0; jt < 4; jt++) {
        const short* brow = &Bs[(jt * 16 + m) * 256];
        float4v c0 = {0.f, 0.f, 0.f, 0.f};
        float4v c1 = {0.f, 0.f, 0.f, 0.f};
        #pragma unroll
        for (int kk = 0; kk < 8; kk++) {
            short8 b = *(const short8*)(brow + (((q + 4 * kk) ^ swz) * 8));
            c0 = __builtin_amdgcn_mfma_f32_16x16x32_bf16(A[0][kk], b, c0, 0, 0, 0);
            c1 = __builtin_amdgcn_mfma_f32_16x16x32_bf16(A[1][kk], b, c1, 0, 0, 0);
        }
        float csum = 0.0f;
        #pragma unroll
        for (int r = 0; r < 4; r++) {
            float e0 = __builtin_exp2f(c0[r]);
            float e1 = __builtin_exp2f(c1[r]);
            rowacc[0][r] += e0; rowacc[1][r] += e1;
            csum += e0 + e1;
        }
        if (do_col) {
            // column jt*16 + m: sum over this wave's 32 rows (LDS combine only)
            csum += __shfl_xor(csum, 16);
            csum += __shfl_xor(csum, 32);
            if (lane < 16) atomicAdd(&cs[jt * 16 + m], csum);
        }
    }

    // row sums: reduce over 16 column-lanes, plain store into Prow[jc][row]
    #pragma unroll
    for (int t = 0; t < 2; t++) {
        #pragma unroll
        for (int r = 0; r < 4; r++) {
            float s = rowacc[t][r];
            s += __shfl_xor(s, 1);
            s += __shfl_xor(s, 2);
            s += __shfl_xor(s, 4);
            s += __shfl_xor(s, 8);
            if (m == 0) Prow[jc * NROWS + ibase + t * 16 + q * 4 + r] = s;
        }
    }
    if (do_col) {
        __syncthreads();
        if (tid < 64) Pcol[ib * NROWS + jbase + tid] = cs[tid];
    }
}

// K3: S_i = sum of 96 contiguous partial planes (Pall = Prow planes 0..63,
// Pcol planes 64..95); loss = mean log(S_i - e^2) - 2*pd[i%NB]. grid 64 x 256:
// block handles 64 rows; 4 plane-quarters per row combined in LDS.
__global__ __launch_bounds__(256) void k_loss(const float* __restrict__ Pall,
                                              const float* __restrict__ pd,
                                              float* __restrict__ out) {
    __shared__ float red2[4][64];
    int tid = threadIdx.x;
    int t = tid & 63, quarter = tid >> 6;
    int row = blockIdx.x * 64 + t;
    float s = 0.0f;
    #pragma unroll
    for (int k = 0; k < 24; k++) {
        int p = quarter * 24 + k;
        s += Pall[(size_t)p * NROWS + row];
    }
    red2[quarter][t] = s;
    __syncthreads();
    if (tid < 64) {
        float tot = red2[0][t] + red2[1][t] + red2[2][t] + red2[3][t];
        const float E2 = 7.38905609893065f;  // exp(sim_ii) = e^2
        float term = logf(tot - E2) - TEMP_INV * pd[row & (NB - 1)];
        #pragma unroll
        for (int off = 32; off > 0; off >>= 1) term += __shfl_xor(term, off);
        if (t == 0) atomicAdd(out, term * (1.0f / NROWS));
    }
}

extern "C" void kernel_launch(void* const* d_in, const int* in_sizes, int n_in,
                              void* d_out, int out_size, void* d_ws, size_t ws_size,
                              hipStream_t stream) {
    const float* zi = (const float*)d_in[0];
    const float* zj = (const float*)d_in[1];
    float* out = (float*)d_out;
    char* ws = (char*)d_ws;
    unsigned short* zb  = (unsigned short*)ws;                          // 2 MB bf16 normalized
    unsigned short* zb2 = (unsigned short*)(ws + 2 * 1024 * 1024);      // 2 MB bf16 * 2log2e
    float* Pall = (float*)(ws + 4 * 1024 * 1024);                       // 96 planes x 4096 = 1.5 MB
    float* Prow = Pall;                                                 // planes 0..63 (by jc)
    float* Pcol = Pall + 64 * NROWS;                                    // planes 64..95 (by ib)
    float* pd   = (float*)(ws + 5 * 1024 * 1024 + 512 * 1024);          // 8 KB pos dots

    hipLaunchKernelGGL(k_norm, dim3(512), dim3(256), 0, stream,
                       zi, zj, zb, zb2, pd, (float4*)Pall, out);
    hipLaunchKernelGGL(k_sim, dim3(NTILES), dim3(256), 0, stream, zb, zb2, Prow, Pcol);
    hipLaunchKernelGGL(k_loss, dim3(64), dim3(256), 0, stream, Pall, pd, out);
}